// Round 11
// baseline (511.248 us; speedup 1.0000x reference)
//
#include <hip/hip_runtime.h>
#include <stdint.h>

namespace {
constexpr int Wd = 960, Hd = 544, Cd = 16, Id = 5, Bd = 2;
constexpr int HW = Hd * Wd;                       // 522240
constexpr long CHW = (long)Cd * HW;               // 8,355,840
constexpr long FRAME_BSTRIDE = (long)Id * CHW;
constexpr long FLOW_BSTRIDE  = (long)Id * 2 * HW;

constexpr int TSX = 64, TSY = 32;   // output tile, 512 thr x 4 px

// fp32-source geometry (stage A)
constexpr int HALO = 12;            // 3 sigma; tails -> epilogue fixup
constexpr int TWX = TSX + 2 * HALO; // 88
constexpr int TWY = TSY + 2 * HALO; // 56
constexpr int NCHUNK = 20;          // 20 x 256 floats = 5120 >= 88*56 = 4928
constexpr int TILE_F = NCHUNK * 256;

// bf16-source geometry (stages B/C/D): halo 16 keeps GLL sources 16B-aligned
constexpr int HB   = 16;
constexpr int TWXB = TSX + 2 * HB;  // 96  (mult of 8 -> lane groups never straddle)
constexpr int TWYB = TSY + 2 * HB;  // 64
constexpr int TILE_B = TWXB * TWYB; // 6144 bf16 = 12 KB; 12 chunks of 512

constexpr int GX = Wd / TSX;        // 15
constexpr int GY = Hd / TSY;        // 17
constexpr int NWG = GX * GY * Bd;   // 510
}

struct F2 { float x, y; };
struct Job { const void* s; long ss; void* d; long ds; const float* fl; int sBF, dBF; };

__device__ __forceinline__ uint f2bf_bits(float v) {   // RNE float->bf16
  uint x = __float_as_uint(v);
  return (x + 0x7FFFu + ((x >> 16) & 1u)) >> 16;
}

// ---------- decode helpers ----------
#define DECODE_TILE()                                                        \
  const int orig = blockIdx.x;                                               \
  const int xcd  = orig & 7;                                                 \
  constexpr int q = NWG / 8, r = NWG % 8;                                    \
  const int wgid = (xcd < r ? xcd * (q + 1) : r * (q + 1) + (xcd - r) * q)   \
                 + (orig >> 3);                                              \
  const int b   = wgid / (GX * GY);                                          \
  const int rem = wgid - b * (GX * GY);                                      \
  const int tyb = rem / GX;                                                  \
  const int txb = rem - tyb * GX;                                            \
  const int X0 = txb * TSX;                                                  \
  const int Y0 = tyb * TSY;                                                  \
  const int t   = threadIdx.x;                                               \
  const int x   = X0 + ((t & 15) << 2);                                      \
  const int y   = Y0 + (t >> 4);                                             \
  const int pix = y * Wd + x;

// lA scale SC_: 4 -> byte offset (fp32 tile), 1 -> element index (bf16 tile)
#define PRECOMPUTE_WEIGHTS(HALO_, TWX_, TWY_, SC_)                           \
  float4 fxv = *reinterpret_cast<const float4*>(fl + pix);                   \
  float4 fyv = *reinterpret_cast<const float4*>(fl + HW + pix);              \
  float w00[4], w10[4], w01[4], w11[4];                                      \
  int lA[4]; uint32_t pxy[4]; int fbm = 0;                                   \
  _Pragma("unroll")                                                          \
  for (int j = 0; j < 4; ++j) {                                              \
    float fx = (j==0)?fxv.x:(j==1)?fxv.y:(j==2)?fxv.z:fxv.w;                 \
    float fy = (j==0)?fyv.x:(j==1)?fyv.y:(j==2)?fyv.z:fyv.w;                 \
    float gx = (float)(x + j) + fx;                                          \
    float gy = (float)y + fy;                                                \
    float x0f = floorf(gx), y0f = floorf(gy);                                \
    float wx = gx - x0f, wy = gy - y0f;                                      \
    bool vx0 = (x0f >= 0.f) && (x0f <= (float)(Wd - 1));                     \
    bool vx1 = (x0f + 1.f >= 0.f) && (x0f + 1.f <= (float)(Wd - 1));         \
    bool vy0 = (y0f >= 0.f) && (y0f <= (float)(Hd - 1));                     \
    bool vy1 = (y0f + 1.f >= 0.f) && (y0f + 1.f <= (float)(Hd - 1));         \
    w00[j] = (1.f-wx)*(1.f-wy) * ((vx0 && vy0) ? 1.f : 0.f);                 \
    w10[j] = wx*(1.f-wy)       * ((vx1 && vy0) ? 1.f : 0.f);                 \
    w01[j] = (1.f-wx)*wy       * ((vx0 && vy1) ? 1.f : 0.f);                 \
    w11[j] = wx*wy             * ((vx1 && vy1) ? 1.f : 0.f);                 \
    int ix0 = (int)x0f;                                                      \
    int iy0 = (int)y0f;                                                      \
    int lx = ix0 - (X0 - (HALO_));                                           \
    int ly = iy0 - (Y0 - (HALO_));                                           \
    bool ft = (lx >= 0) & (lx <= (TWX_) - 2) & (ly >= 0) & (ly <= (TWY_) - 2);\
    if (!ft) fbm |= (1 << j);                                                \
    int lxc = min(max(lx, 0), (TWX_) - 2), lyc = min(max(ly, 0), (TWY_) - 2);\
    lA[j] = (lyc * (TWX_) + lxc) * (SC_);                                    \
    uint32_t px_ = (uint32_t)min(max(ix0 + 128, 0), 65535);                  \
    uint32_t py_ = (uint32_t)min(max(iy0 + 128, 0), 65535);                  \
    pxy[j] = px_ | (py_ << 16);                                              \
  }

#define WAITV(n3, n2)                                                        \
  if (wv < 4) { asm volatile("s_waitcnt vmcnt(" #n3 ")" ::: "memory"); }     \
  else        { asm volatile("s_waitcnt vmcnt(" #n2 ")" ::: "memory"); }

// =============== pipelined fp32-source kernel (stage A) — round-9 proven ===
#define PHASE(c, n3, n2)                                                     \
  WAITV(n3, n2);                                                             \
  __builtin_amdgcn_s_barrier();                                              \
  __builtin_amdgcn_sched_barrier(0);                                         \
  if ((c) + 3 < Cd) fillq(((c) + 3) & 3, (c) + 3);                           \
  comp(c);

__global__ __launch_bounds__(512, 4) void warp_pipe(
    Job j0, Job j1, Job j2, Job j3, Job j4)
{
  __shared__ float tile[4 * TILE_F];   // 80 KB -> 2 blocks/CU

  const int jb = blockIdx.y;
  Job J = j0;
  if      (jb == 1) J = j1;
  else if (jb == 2) J = j2;
  else if (jb == 3) J = j3;
  else if (jb == 4) J = j4;

  DECODE_TILE();

  const float* sF32 = (const float*)J.s + (long)b * J.ss;
  float*       dF32 = (float*)J.d + (long)b * J.ds;
  uint16_t*    dB16 = (uint16_t*)J.d + (long)b * J.ds;
  const bool dBF = J.dBF != 0;

  if (J.fl == nullptr) {   // plain fp32 copy job (frame 0); no barriers
#pragma unroll
    for (int c = 0; c < Cd; ++c)
      *reinterpret_cast<float4*>(dF32 + (long)c * HW + pix)
          = *reinterpret_cast<const float4*>(sF32 + (long)c * HW + pix);
    return;
  }

  const float* fl = J.fl + (long)b * FLOW_BSTRIDE;
  PRECOMPUTE_WEIGHTS(HALO, TWX, TWY, 4);

  const int lane = t & 63;
  const int wv   = t >> 6;
  const int nck  = (wv < 4) ? 3 : 2;
  int goff[3];
#pragma unroll
  for (int k = 0; k < 3; ++k) {
    int ck = wv + 8 * k;
    if (ck < NCHUNK) {
      int foff = ck * 256 + lane * 4;
      int ly = foff / TWX;
      int lx = foff - ly * TWX;
      int gxc = min(max(X0 - HALO + lx, 0), Wd - 4);
      int gyc = min(max(Y0 - HALO + ly, 0), Hd - 1);
      goff[k] = gyc * Wd + gxc;
    }
  }

  auto fillq = [&](int buf, int c) {
    const float* sC = sF32 + (long)c * HW;
    float* base = &tile[buf * TILE_F];
#pragma unroll
    for (int k = 0; k < 3; ++k) {
      if (k < nck) {
        __builtin_amdgcn_global_load_lds(
            (__attribute__((address_space(1))) void*)(void*)(sC + goff[k]),
            (__attribute__((address_space(3))) void*)&base[(wv + 8 * k) * 256],
            16, 0, 0);
      }
    }
  };

  auto comp = [&](int c) {
    const float* tb = &tile[(c & 3) * TILE_F];
    float ov[4];
#pragma unroll
    for (int j = 0; j < 4; ++j) {
      F2 r0 = *(const F2*)((const char*)tb + lA[j]);
      F2 r1 = *(const F2*)((const char*)tb + lA[j] + TWX * 4);
      ov[j] = (w00[j] * r0.x + w10[j] * r0.y) + (w01[j] * r1.x + w11[j] * r1.y);
    }
    if (dBF) {
      uint p0 = f2bf_bits(ov[0]) | (f2bf_bits(ov[1]) << 16);
      uint p1 = f2bf_bits(ov[2]) | (f2bf_bits(ov[3]) << 16);
      *reinterpret_cast<uint2*>(dB16 + (long)c * HW + pix) = make_uint2(p0, p1);
    } else {
      *reinterpret_cast<float4*>(dF32 + (long)c * HW + pix)
          = make_float4(ov[0], ov[1], ov[2], ov[3]);
    }
  };

  fillq(0, 0); fillq(1, 1); fillq(2, 2);

  PHASE(0, 6, 4)  PHASE(1, 7, 5)  PHASE(2, 8, 6)
  PHASE(3, 9, 7)  PHASE(4, 9, 7)  PHASE(5, 9, 7)
  PHASE(6, 9, 7)  PHASE(7, 9, 7)  PHASE(8, 9, 7)
  PHASE(9, 9, 7)  PHASE(10, 9, 7) PHASE(11, 9, 7)
  PHASE(12, 9, 7) PHASE(13, 9, 7)
  PHASE(14, 6, 5) PHASE(15, 3, 3)

  if (fbm) {
    asm volatile("s_waitcnt vmcnt(0)" ::: "memory");
    for (int c = 0; c < Cd; ++c) {
      const float* sC = sF32 + (long)c * HW;
#pragma unroll
      for (int j = 0; j < 4; ++j) {
        if (fbm & (1 << j)) {
          uint32_t p = pxy[j];
          int ix0 = (int)(p & 0xffffu) - 128;
          int iy0 = (int)(p >> 16) - 128;
          int xc0 = min(max(ix0, 0), Wd - 1), xc1 = min(max(ix0 + 1, 0), Wd - 1);
          int yc0 = min(max(iy0, 0), Hd - 1), yc1 = min(max(iy0 + 1, 0), Hd - 1);
          float v = w00[j] * sC[yc0 * Wd + xc0] + w10[j] * sC[yc0 * Wd + xc1]
                  + w01[j] * sC[yc1 * Wd + xc0] + w11[j] * sC[yc1 * Wd + xc1];
          if (dBF) dB16[(long)c * HW + pix + j] = (uint16_t)f2bf_bits(v);
          else     dF32[(long)c * HW + pix + j] = v;
        }
      }
    }
  }
}

// ======= pipelined bf16-source kernel (stages B/C/D): GLL + bf16 tile ======
// Same schedule as warp_pipe; tile is bf16 (12 KB x 4 = 48 KB), GLL moves
// raw bf16, gather reads 4x ds_read_u16 + shift-cvt. Per-phase vmem ops =
// nck fills + 1 store with nck in {2,1} -> steady vmcnt(7/5).
#define BPH(c, n2, n1)                                                       \
  if (wv < 4) { asm volatile("s_waitcnt vmcnt(" #n2 ")" ::: "memory"); }     \
  else        { asm volatile("s_waitcnt vmcnt(" #n1 ")" ::: "memory"); }     \
  __builtin_amdgcn_s_barrier();                                              \
  __builtin_amdgcn_sched_barrier(0);                                         \
  if ((c) + 3 < Cd) fillb(((c) + 3) & 3, (c) + 3);                           \
  compb(c);

__global__ __launch_bounds__(512, 4) void warp_bf16p(Job j0, Job j1, Job j2)
{
  __shared__ uint16_t tileB[4][TILE_B];   // 48 KB

  const int jb = blockIdx.y;
  Job J = j0;
  if      (jb == 1) J = j1;
  else if (jb == 2) J = j2;

  DECODE_TILE();

  const uint16_t* sB16 = (const uint16_t*)J.s + (long)b * J.ss;
  float*          dF32 = (float*)J.d + (long)b * J.ds;
  uint16_t*       dB16 = (uint16_t*)J.d + (long)b * J.ds;
  const bool dBF = J.dBF != 0;

  const float* fl = J.fl + (long)b * FLOW_BSTRIDE;
  PRECOMPUTE_WEIGHTS(HB, TWXB, TWYB, 1);   // lA = element index

  // 12 chunks of 512 bf16 (1 KB). Wave wv owns {wv, wv+8 if <12}.
  // Lane group = 8 consecutive bf16 (16 B). TWXB=96 is a multiple of 8 and
  // X0-16 is 8-aligned -> every GLL source address is 16B-aligned, groups
  // never straddle rows.
  const int lane = t & 63;
  const int wv   = t >> 6;
  const int nck  = (wv < 4) ? 2 : 1;
  int goff[2];
#pragma unroll
  for (int k = 0; k < 2; ++k) {
    int ck = wv + 8 * k;
    if (ck < 12) {
      int foff = ck * 512 + lane * 8;
      int ly = foff / TWXB;
      int lx = foff - ly * TWXB;
      int gxc = min(max(X0 - HB + lx, 0), Wd - 8);   // Wd-8 keeps 8-alignment
      int gyc = min(max(Y0 - HB + ly, 0), Hd - 1);
      goff[k] = gyc * Wd + gxc;
    }
  }

  auto fillb = [&](int buf, int c) {
    const uint16_t* sC = sB16 + (long)c * HW;
#pragma unroll
    for (int k = 0; k < 2; ++k) {
      if (k < nck) {
        __builtin_amdgcn_global_load_lds(
            (__attribute__((address_space(1))) void*)(void*)(sC + goff[k]),
            (__attribute__((address_space(3))) void*)&tileB[buf][(wv + 8 * k) * 512],
            16, 0, 0);
      }
    }
  };

  auto compb = [&](int c) {
    const uint16_t* tb = tileB[c & 3];
    float ov[4];
#pragma unroll
    for (int j = 0; j < 4; ++j) {
      int ib = lA[j];
      float v00 = __uint_as_float((uint)tb[ib]        << 16);
      float v10 = __uint_as_float((uint)tb[ib + 1]    << 16);
      float v01 = __uint_as_float((uint)tb[ib + TWXB] << 16);
      float v11 = __uint_as_float((uint)tb[ib + TWXB + 1] << 16);
      ov[j] = (w00[j] * v00 + w10[j] * v10) + (w01[j] * v01 + w11[j] * v11);
    }
    if (dBF) {
      uint p0 = f2bf_bits(ov[0]) | (f2bf_bits(ov[1]) << 16);
      uint p1 = f2bf_bits(ov[2]) | (f2bf_bits(ov[3]) << 16);
      *reinterpret_cast<uint2*>(dB16 + (long)c * HW + pix) = make_uint2(p0, p1);
    } else {
      *reinterpret_cast<float4*>(dF32 + (long)c * HW + pix)
          = make_float4(ov[0], ov[1], ov[2], ov[3]);
    }
  };

  fillb(0, 0); fillb(1, 1); fillb(2, 2);

  BPH(0, 4, 2)   BPH(1, 5, 3)   BPH(2, 6, 4)
  BPH(3, 7, 5)   BPH(4, 7, 5)   BPH(5, 7, 5)
  BPH(6, 7, 5)   BPH(7, 7, 5)   BPH(8, 7, 5)
  BPH(9, 7, 5)   BPH(10, 7, 5)  BPH(11, 7, 5)
  BPH(12, 7, 5)  BPH(13, 7, 5)
  BPH(14, 5, 4)  BPH(15, 3, 3)

  if (fbm) {
    asm volatile("s_waitcnt vmcnt(0)" ::: "memory");
    for (int c = 0; c < Cd; ++c) {
      const uint16_t* su = sB16 + (long)c * HW;
#pragma unroll
      for (int j = 0; j < 4; ++j) {
        if (fbm & (1 << j)) {
          uint32_t p = pxy[j];
          int ix0 = (int)(p & 0xffffu) - 128;
          int iy0 = (int)(p >> 16) - 128;
          int xc0 = min(max(ix0, 0), Wd - 1), xc1 = min(max(ix0 + 1, 0), Wd - 1);
          int yc0 = min(max(iy0, 0), Hd - 1), yc1 = min(max(iy0 + 1, 0), Hd - 1);
          float v00 = __uint_as_float((uint)su[yc0 * Wd + xc0] << 16);
          float v10 = __uint_as_float((uint)su[yc0 * Wd + xc1] << 16);
          float v01 = __uint_as_float((uint)su[yc1 * Wd + xc0] << 16);
          float v11 = __uint_as_float((uint)su[yc1 * Wd + xc1] << 16);
          float v = w00[j] * v00 + w10[j] * v10 + w01[j] * v01 + w11[j] * v11;
          if (dBF) dB16[(long)c * HW + pix + j] = (uint16_t)f2bf_bits(v);
          else     dF32[(long)c * HW + pix + j] = v;
        }
      }
    }
  }
}

extern "C" void kernel_launch(void* const* d_in, const int* in_sizes, int n_in,
                              void* d_out, int out_size, void* d_ws, size_t ws_size,
                              hipStream_t stream) {
  const float* feat = (const float*)d_in[0];
  const float* mv   = (const float*)d_in[1];
  float*       out  = (float*)d_out;

  dim3 block(512, 1, 1);
  const long FB = FRAME_BSTRIDE;
  auto mkjob = [](const void* s, long ss, void* d, long ds, const float* fl,
                  int sBF, int dBF) {
    Job j; j.s = s; j.ss = ss; j.d = d; j.ds = ds; j.fl = fl;
    j.sBF = sBF; j.dBF = dBF; return j;
  };
  Job Z = mkjob(nullptr, 0, nullptr, 0, nullptr, 0, 0);
  const float* flj[4] = { mv + 0L * 2 * HW, mv + 1L * 2 * HW,
                          mv + 2L * 2 * HW, mv + 3L * 2 * HW };

  auto launchP = [&](int nj, Job a, Job b, Job c, Job d, Job e) {
    warp_pipe<<<dim3(NWG, nj, 1), block, 0, stream>>>(a, b, c, d, e);
  };
  auto launchB = [&](int nj, Job a, Job b, Job c) {
    warp_bf16p<<<dim3(NWG, nj, 1), block, 0, stream>>>(a, b, c);
  };

  const size_t need = (size_t)(4 * CHW) * Bd * sizeof(uint16_t);  // 134 MB

  if (ws_size >= need) {
    uint16_t* W  = (uint16_t*)d_ws;
    const long WB = 4 * CHW;               // ws batch stride (bf16 elems)
    uint16_t* wa = W + 0 * CHW;
    uint16_t* wb = W + 1 * CHW;
    uint16_t* wd = W + 2 * CHW;
    uint16_t* wc = W + 3 * CHW;
    uint16_t* we = (uint16_t*)(out + 4 * CHW);   // out4 slot as bf16 scratch
    const long EB = 2 * FB;                // out batch stride in bf16 elems

    // A (pipelined fp32): f1 final; f2->a, f3->b, f4->d (bf16); frame-0 copy.
    launchP(5,
      mkjob(feat + 1 * CHW, FB, out + 1 * CHW, FB, flj[0], 0, 0),
      mkjob(feat + 2 * CHW, FB, wa, WB, flj[1], 0, 1),
      mkjob(feat + 3 * CHW, FB, wb, WB, flj[2], 0, 1),
      mkjob(feat + 4 * CHW, FB, wd, WB, flj[3], 0, 1),
      mkjob(feat, FB, out, FB, nullptr, 0, 0));
    // B: a->out2 final; b->c (bf16); d->e (bf16, in out4 slot).
    launchB(3,
      mkjob(wa, WB, out + 2 * CHW, FB, flj[0], 1, 0),
      mkjob(wb, WB, wc, WB, flj[1], 1, 1),
      mkjob(wd, WB, we, EB, flj[2], 1, 1));
    // C: c->out3 final; e->f (bf16, reuse slot a).
    launchB(2,
      mkjob(wc, WB, out + 3 * CHW, FB, flj[0], 1, 0),
      mkjob(we, EB, wa, WB, flj[1], 1, 1), Z);
    // D: f->out4 final (overwrites e, dead).
    launchB(1, mkjob(wa, WB, out + 4 * CHW, FB, flj[0], 1, 0), Z, Z);
  } else {
    // Fallback: all-fp32 via the pipelined kernel, out0 slot as scratch.
    float* S = out;
    auto w1 = [&](const float* s, float* d, int j) {
      launchP(1, mkjob(s, FB, d, FB, flj[j], 0, 0), Z, Z, Z, Z);
    };
    w1(feat + 1 * CHW, out + 1 * CHW, 0);
    w1(feat + 2 * CHW, S, 1);
    w1(S, out + 2 * CHW, 0);
    w1(feat + 3 * CHW, out + 3 * CHW, 2);
    w1(out + 3 * CHW, S, 1);
    w1(S, out + 3 * CHW, 0);
    w1(feat + 4 * CHW, S, 3);
    w1(S, out + 4 * CHW, 2);
    w1(out + 4 * CHW, S, 1);
    w1(S, out + 4 * CHW, 0);
    launchP(1, mkjob(feat, FB, out, FB, nullptr, 0, 0), Z, Z, Z, Z);
  }
}

// Round 12
// 300.216 us; speedup vs baseline: 1.7029x; 1.7029x over previous
//
#include <hip/hip_runtime.h>
#include <stdint.h>

namespace {
constexpr int Wd = 960, Hd = 544, Cd = 16, Id = 5, Bd = 2;
constexpr int HW = Hd * Wd;                       // 522240
constexpr long CHW = (long)Cd * HW;               // 8,355,840
constexpr long FRAME_BSTRIDE = (long)Id * CHW;
constexpr long FLOW_BSTRIDE  = (long)Id * 2 * HW;

constexpr int TSX = 64, TSY = 32;   // output tile, 512 thr x 4 px
constexpr int HALO = 12;            // 3 sigma of 4px flow; tails -> epilogue fixup
constexpr int TWX = TSX + 2 * HALO; // 88
constexpr int TWY = TSY + 2 * HALO; // 56
constexpr int NCHUNK = 20;          // 20 x 256 floats = 5120 >= 88*56 = 4928
constexpr int TILE_F = NCHUNK * 256;  // max read idx 54*88+86+89 = 4927 < 5120
constexpr int GX = Wd / TSX;        // 15
constexpr int GY = Hd / TSY;        // 17
constexpr int NWG = GX * GY * Bd;   // 510
}

struct F2 { float x, y; };
struct Job { const void* s; long ss; void* d; long ds; const float* fl; int sBF, dBF; };

__device__ __forceinline__ uint f2bf_bits(float v) {   // RNE float->bf16
  uint x = __float_as_uint(v);
  return (x + 0x7FFFu + ((x >> 16) & 1u)) >> 16;
}

// ---------- decode helpers ----------
#define DECODE_TILE()                                                        \
  const int orig = blockIdx.x;                                               \
  const int xcd  = orig & 7;                                                 \
  constexpr int q = NWG / 8, r = NWG % 8;                                    \
  const int wgid = (xcd < r ? xcd * (q + 1) : r * (q + 1) + (xcd - r) * q)   \
                 + (orig >> 3);                                              \
  const int b   = wgid / (GX * GY);                                          \
  const int rem = wgid - b * (GX * GY);                                      \
  const int tyb = rem / GX;                                                  \
  const int txb = rem - tyb * GX;                                            \
  const int X0 = txb * TSX;                                                  \
  const int Y0 = tyb * TSY;                                                  \
  const int t   = threadIdx.x;                                               \
  const int x   = X0 + ((t & 15) << 2);                                      \
  const int y   = Y0 + (t >> 4);                                             \
  const int pix = y * Wd + x;

#define PRECOMPUTE_WEIGHTS()                                                 \
  float4 fxv = *reinterpret_cast<const float4*>(fl + pix);                   \
  float4 fyv = *reinterpret_cast<const float4*>(fl + HW + pix);              \
  float w00[4], w10[4], w01[4], w11[4];                                      \
  int lA[4]; uint32_t pxy[4]; int fbm = 0;                                   \
  _Pragma("unroll")                                                          \
  for (int j = 0; j < 4; ++j) {                                              \
    float fx = (j==0)?fxv.x:(j==1)?fxv.y:(j==2)?fxv.z:fxv.w;                 \
    float fy = (j==0)?fyv.x:(j==1)?fyv.y:(j==2)?fyv.z:fyv.w;                 \
    float gx = (float)(x + j) + fx;                                          \
    float gy = (float)y + fy;                                                \
    float x0f = floorf(gx), y0f = floorf(gy);                                \
    float wx = gx - x0f, wy = gy - y0f;                                      \
    bool vx0 = (x0f >= 0.f) && (x0f <= (float)(Wd - 1));                     \
    bool vx1 = (x0f + 1.f >= 0.f) && (x0f + 1.f <= (float)(Wd - 1));         \
    bool vy0 = (y0f >= 0.f) && (y0f <= (float)(Hd - 1));                     \
    bool vy1 = (y0f + 1.f >= 0.f) && (y0f + 1.f <= (float)(Hd - 1));         \
    w00[j] = (1.f-wx)*(1.f-wy) * ((vx0 && vy0) ? 1.f : 0.f);                 \
    w10[j] = wx*(1.f-wy)       * ((vx1 && vy0) ? 1.f : 0.f);                 \
    w01[j] = (1.f-wx)*wy       * ((vx0 && vy1) ? 1.f : 0.f);                 \
    w11[j] = wx*wy             * ((vx1 && vy1) ? 1.f : 0.f);                 \
    int ix0 = (int)x0f;                                                      \
    int iy0 = (int)y0f;                                                      \
    int lx = ix0 - (X0 - HALO);                                              \
    int ly = iy0 - (Y0 - HALO);                                              \
    bool ft = (lx >= 0) & (lx <= TWX - 2) & (ly >= 0) & (ly <= TWY - 2);     \
    if (!ft) fbm |= (1 << j);                                                \
    int lxc = min(max(lx, 0), TWX - 2), lyc = min(max(ly, 0), TWY - 2);      \
    lA[j] = (lyc * TWX + lxc) * 4;                                           \
    uint32_t px_ = (uint32_t)min(max(ix0 + 128, 0), 65535);                  \
    uint32_t py_ = (uint32_t)min(max(iy0 + 128, 0), 65535);                  \
    pxy[j] = px_ | (py_ << 16);                                              \
  }

#define PRECOMPUTE_GOFF()                                                    \
  const int lane = t & 63;                                                   \
  const int wv   = t >> 6;                                                   \
  const int nck  = (wv < 4) ? 3 : 2;                                         \
  int goff[3];                                                               \
  _Pragma("unroll")                                                          \
  for (int k = 0; k < 3; ++k) {                                              \
    int ck = wv + 8 * k;                                                     \
    if (ck < NCHUNK) {                                                       \
      int foff = ck * 256 + lane * 4;                                        \
      int ly = foff / TWX;                                                   \
      int lx = foff - ly * TWX;                                              \
      int gxc = min(max(X0 - HALO + lx, 0), Wd - 4);                         \
      int gyc = min(max(Y0 - HALO + ly, 0), Hd - 1);                         \
      goff[k] = gyc * Wd + gxc;                                              \
    }                                                                        \
  }

#define WAITV(n3, n2)                                                        \
  if (wv < 4) { asm volatile("s_waitcnt vmcnt(" #n3 ")" ::: "memory"); }     \
  else        { asm volatile("s_waitcnt vmcnt(" #n2 ")" ::: "memory"); }

// =============== pipelined fp32-source kernel (stage A + fallback) =========
#define PHASE(c, n3, n2)                                                     \
  WAITV(n3, n2);                                                             \
  __builtin_amdgcn_s_barrier();                                              \
  __builtin_amdgcn_sched_barrier(0);                                         \
  if ((c) + 3 < Cd) fillq(((c) + 3) & 3, (c) + 3);                           \
  comp(c);

__global__ __launch_bounds__(512, 4) void warp_pipe(
    Job j0, Job j1, Job j2, Job j3, Job j4)
{
  __shared__ float tile[4 * TILE_F];   // 80 KB -> 2 blocks/CU

  const int jb = blockIdx.y;
  Job J = j0;
  if      (jb == 1) J = j1;
  else if (jb == 2) J = j2;
  else if (jb == 3) J = j3;
  else if (jb == 4) J = j4;

  DECODE_TILE();

  const float* sF32 = (const float*)J.s + (long)b * J.ss;
  float*       dF32 = (float*)J.d + (long)b * J.ds;
  uint16_t*    dB16 = (uint16_t*)J.d + (long)b * J.ds;
  const bool dBF = J.dBF != 0;

  if (J.fl == nullptr) {   // plain fp32 copy job (frame 0); no barriers
#pragma unroll
    for (int c = 0; c < Cd; ++c)
      *reinterpret_cast<float4*>(dF32 + (long)c * HW + pix)
          = *reinterpret_cast<const float4*>(sF32 + (long)c * HW + pix);
    return;
  }

  const float* fl = J.fl + (long)b * FLOW_BSTRIDE;
  PRECOMPUTE_WEIGHTS();
  PRECOMPUTE_GOFF();

  auto fillq = [&](int buf, int c) {
    const float* sC = sF32 + (long)c * HW;
    float* base = &tile[buf * TILE_F];
#pragma unroll
    for (int k = 0; k < 3; ++k) {
      if (k < nck) {
        __builtin_amdgcn_global_load_lds(
            (__attribute__((address_space(1))) void*)(void*)(sC + goff[k]),
            (__attribute__((address_space(3))) void*)&base[(wv + 8 * k) * 256],
            16, 0, 0);
      }
    }
  };

  auto comp = [&](int c) {
    const float* tb = &tile[(c & 3) * TILE_F];
    float ov[4];
#pragma unroll
    for (int j = 0; j < 4; ++j) {
      F2 r0 = *(const F2*)((const char*)tb + lA[j]);
      F2 r1 = *(const F2*)((const char*)tb + lA[j] + TWX * 4);
      ov[j] = (w00[j] * r0.x + w10[j] * r0.y) + (w01[j] * r1.x + w11[j] * r1.y);
    }
    if (dBF) {
      uint p0 = f2bf_bits(ov[0]) | (f2bf_bits(ov[1]) << 16);
      uint p1 = f2bf_bits(ov[2]) | (f2bf_bits(ov[3]) << 16);
      *reinterpret_cast<uint2*>(dB16 + (long)c * HW + pix) = make_uint2(p0, p1);
    } else {
      *reinterpret_cast<float4*>(dF32 + (long)c * HW + pix)
          = make_float4(ov[0], ov[1], ov[2], ov[3]);
    }
  };

  fillq(0, 0); fillq(1, 1); fillq(2, 2);

  PHASE(0, 6, 4)  PHASE(1, 7, 5)  PHASE(2, 8, 6)
  PHASE(3, 9, 7)  PHASE(4, 9, 7)  PHASE(5, 9, 7)
  PHASE(6, 9, 7)  PHASE(7, 9, 7)  PHASE(8, 9, 7)
  PHASE(9, 9, 7)  PHASE(10, 9, 7) PHASE(11, 9, 7)
  PHASE(12, 9, 7) PHASE(13, 9, 7)
  PHASE(14, 6, 5) PHASE(15, 3, 3)

  if (fbm) {
    asm volatile("s_waitcnt vmcnt(0)" ::: "memory");
    for (int c = 0; c < Cd; ++c) {
      const float* sC = sF32 + (long)c * HW;
#pragma unroll
      for (int j = 0; j < 4; ++j) {
        if (fbm & (1 << j)) {
          uint32_t p = pxy[j];
          int ix0 = (int)(p & 0xffffu) - 128;
          int iy0 = (int)(p >> 16) - 128;
          int xc0 = min(max(ix0, 0), Wd - 1), xc1 = min(max(ix0 + 1, 0), Wd - 1);
          int yc0 = min(max(iy0, 0), Hd - 1), yc1 = min(max(iy0 + 1, 0), Hd - 1);
          float v = w00[j] * sC[yc0 * Wd + xc0] + w10[j] * sC[yc0 * Wd + xc1]
                  + w01[j] * sC[yc1 * Wd + xc0] + w11[j] * sC[yc1 * Wd + xc1];
          if (dBF) dB16[(long)c * HW + pix + j] = (uint16_t)f2bf_bits(v);
          else     dF32[(long)c * HW + pix + j] = v;
        }
      }
    }
  }
}

// =============== bf16-source kernel (stages B/C/D) — round-8 proven ========
__global__ __launch_bounds__(512) void warp_bf16(
    Job j0, Job j1, Job j2, Job j3, Job j4)
{
  __shared__ float tile[2][TILE_F];   // 40 KB

  const int jb = blockIdx.y;
  Job J = j0;
  if      (jb == 1) J = j1;
  else if (jb == 2) J = j2;

  DECODE_TILE();

  const uint16_t* sB16 = (const uint16_t*)J.s + (long)b * J.ss;
  float*          dF32 = (float*)J.d + (long)b * J.ds;
  uint16_t*       dB16 = (uint16_t*)J.d + (long)b * J.ds;
  const bool dBF = J.dBF != 0;

  const float* fl = J.fl + (long)b * FLOW_BSTRIDE;
  PRECOMPUTE_WEIGHTS();
  PRECOMPUTE_GOFF();

  // bf16 fill: reg-staged (load early / cvt+ds_write late).
  uint2 ld[3];
  auto loadB = [&](int c) {
    const uint* gp = (const uint*)(sB16 + (long)c * HW);
#pragma unroll
    for (int k = 0; k < 3; ++k)
      if (k < nck) ld[k] = *(const uint2*)(gp + (goff[k] >> 1));
  };
  auto writeB = [&](int nb) {
#pragma unroll
    for (int k = 0; k < 3; ++k) {
      if (k < nck) {
        float4 f;
        f.x = __uint_as_float(ld[k].x << 16);
        f.y = __uint_as_float(ld[k].x & 0xFFFF0000u);
        f.z = __uint_as_float(ld[k].y << 16);
        f.w = __uint_as_float(ld[k].y & 0xFFFF0000u);
        *reinterpret_cast<float4*>(&tile[nb][(wv + 8 * k) * 256 + lane * 4]) = f;
      }
    }
  };

  loadB(0); writeB(0);

#pragma unroll
  for (int c = 0; c < Cd; ++c) {
    __syncthreads();
    const bool pre = (c + 1 < Cd);
    if (pre) loadB(c + 1);

    const float* tb = tile[c & 1];
    float ov[4];
#pragma unroll
    for (int j = 0; j < 4; ++j) {
      float v;
      if (!(fbm & (1 << j))) {
        F2 r0 = *(const F2*)((const char*)tb + lA[j]);
        F2 r1 = *(const F2*)((const char*)tb + lA[j] + TWX * 4);
        v = (w00[j] * r0.x + w10[j] * r0.y) + (w01[j] * r1.x + w11[j] * r1.y);
      } else {
        uint32_t p = pxy[j];
        int ix0 = (int)(p & 0xffffu) - 128;
        int iy0 = (int)(p >> 16) - 128;
        int xc0 = min(max(ix0, 0), Wd - 1), xc1 = min(max(ix0 + 1, 0), Wd - 1);
        int yc0 = min(max(iy0, 0), Hd - 1), yc1 = min(max(iy0 + 1, 0), Hd - 1);
        const uint16_t* su = sB16 + (long)c * HW;
        float v00 = __uint_as_float((uint)su[yc0 * Wd + xc0] << 16);
        float v10 = __uint_as_float((uint)su[yc0 * Wd + xc1] << 16);
        float v01 = __uint_as_float((uint)su[yc1 * Wd + xc0] << 16);
        float v11 = __uint_as_float((uint)su[yc1 * Wd + xc1] << 16);
        v = w00[j] * v00 + w10[j] * v10 + w01[j] * v01 + w11[j] * v11;
      }
      ov[j] = v;
    }
    if (dBF) {
      uint p0 = f2bf_bits(ov[0]) | (f2bf_bits(ov[1]) << 16);
      uint p1 = f2bf_bits(ov[2]) | (f2bf_bits(ov[3]) << 16);
      *reinterpret_cast<uint2*>(dB16 + (long)c * HW + pix) = make_uint2(p0, p1);
    } else {
      *reinterpret_cast<float4*>(dF32 + (long)c * HW + pix)
          = make_float4(ov[0], ov[1], ov[2], ov[3]);
    }
    if (pre) writeB((c + 1) & 1);
  }
}

extern "C" void kernel_launch(void* const* d_in, const int* in_sizes, int n_in,
                              void* d_out, int out_size, void* d_ws, size_t ws_size,
                              hipStream_t stream) {
  const float* feat = (const float*)d_in[0];
  const float* mv   = (const float*)d_in[1];
  float*       out  = (float*)d_out;

  dim3 block(512, 1, 1);
  const long FB = FRAME_BSTRIDE;
  auto mkjob = [](const void* s, long ss, void* d, long ds, const float* fl,
                  int sBF, int dBF) {
    Job j; j.s = s; j.ss = ss; j.d = d; j.ds = ds; j.fl = fl;
    j.sBF = sBF; j.dBF = dBF; return j;
  };
  Job Z = mkjob(nullptr, 0, nullptr, 0, nullptr, 0, 0);
  const float* flj[4] = { mv + 0L * 2 * HW, mv + 1L * 2 * HW,
                          mv + 2L * 2 * HW, mv + 3L * 2 * HW };

  auto launchP = [&](int nj, Job a, Job b, Job c, Job d, Job e) {
    warp_pipe<<<dim3(NWG, nj, 1), block, 0, stream>>>(a, b, c, d, e);
  };
  auto launchB = [&](int nj, Job a, Job b, Job c) {
    warp_bf16<<<dim3(NWG, nj, 1), block, 0, stream>>>(a, b, c, Z, Z);
  };

  const size_t need = (size_t)(4 * CHW) * Bd * sizeof(uint16_t);  // 134 MB

  if (ws_size >= need) {
    uint16_t* W  = (uint16_t*)d_ws;
    const long WB = 4 * CHW;               // ws batch stride (bf16 elems)
    uint16_t* wa = W + 0 * CHW;
    uint16_t* wb = W + 1 * CHW;
    uint16_t* wd = W + 2 * CHW;
    uint16_t* wc = W + 3 * CHW;
    uint16_t* we = (uint16_t*)(out + 4 * CHW);   // out4 slot as bf16 scratch
    const long EB = 2 * FB;                // out batch stride in bf16 elems

    // A (pipelined fp32): f1 final; f2->a, f3->b, f4->d (bf16); frame-0 copy.
    launchP(5,
      mkjob(feat + 1 * CHW, FB, out + 1 * CHW, FB, flj[0], 0, 0),
      mkjob(feat + 2 * CHW, FB, wa, WB, flj[1], 0, 1),
      mkjob(feat + 3 * CHW, FB, wb, WB, flj[2], 0, 1),
      mkjob(feat + 4 * CHW, FB, wd, WB, flj[3], 0, 1),
      mkjob(feat, FB, out, FB, nullptr, 0, 0));
    // B: a->out2 final; b->c (bf16); d->e (bf16, in out4 slot).
    launchB(3,
      mkjob(wa, WB, out + 2 * CHW, FB, flj[0], 1, 0),
      mkjob(wb, WB, wc, WB, flj[1], 1, 1),
      mkjob(wd, WB, we, EB, flj[2], 1, 1));
    // C: c->out3 final; e->f (bf16, reuse slot a).
    launchB(2,
      mkjob(wc, WB, out + 3 * CHW, FB, flj[0], 1, 0),
      mkjob(we, EB, wa, WB, flj[1], 1, 1), Z);
    // D: f->out4 final (overwrites e, dead).
    launchB(1, mkjob(wa, WB, out + 4 * CHW, FB, flj[0], 1, 0), Z, Z);
  } else {
    // Fallback: all-fp32 via the pipelined kernel, out0 slot as scratch.
    float* S = out;
    auto w1 = [&](const float* s, float* d, int j) {
      launchP(1, mkjob(s, FB, d, FB, flj[j], 0, 0), Z, Z, Z, Z);
    };
    w1(feat + 1 * CHW, out + 1 * CHW, 0);
    w1(feat + 2 * CHW, S, 1);
    w1(S, out + 2 * CHW, 0);
    w1(feat + 3 * CHW, out + 3 * CHW, 2);
    w1(out + 3 * CHW, S, 1);
    w1(S, out + 3 * CHW, 0);
    w1(feat + 4 * CHW, S, 3);
    w1(S, out + 4 * CHW, 2);
    w1(out + 4 * CHW, S, 1);
    w1(S, out + 4 * CHW, 0);
    launchP(1, mkjob(feat, FB, out, FB, nullptr, 0, 0), Z, Z, Z, Z);
  }
}